// Round 2
// baseline (429.115 us; speedup 1.0000x reference)
//
#include <hip/hip_runtime.h>
#include <hip/hip_bf16.h>

#define N_NODES 4096
#define N_EDGES 131072

typedef short bf16x8 __attribute__((ext_vector_type(8)));
typedef float f32x4  __attribute__((ext_vector_type(4)));

static __device__ __forceinline__ float b2f(__hip_bfloat16 x) { return __bfloat162float(x); }
static __device__ __forceinline__ __hip_bfloat16 f2b(float x) { return __float2bfloat16(x); }
static __device__ __forceinline__ short f2bs(float x) {
    __hip_bfloat16 h = __float2bfloat16(x);
    return *reinterpret_cast<short*>(&h);
}

static __device__ __forceinline__ float rmax16(float v) {
    v = fmaxf(v, __shfl_xor(v, 1));
    v = fmaxf(v, __shfl_xor(v, 2));
    v = fmaxf(v, __shfl_xor(v, 4));
    v = fmaxf(v, __shfl_xor(v, 8));
    return v;
}
static __device__ __forceinline__ float rsum16(float v) {
    v += __shfl_xor(v, 1);
    v += __shfl_xor(v, 2);
    v += __shfl_xor(v, 4);
    v += __shfl_xor(v, 8);
    return v;
}

// ------------------------------------------------------------ dtype probe
// flags[0]=1 -> float inputs are f32 ; flags[1]=1 -> edge_index is int64
__global__ void probe_k(const unsigned* __restrict__ ln1g_raw,
                        const unsigned* __restrict__ ei_raw, int* flags) {
    if (threadIdx.x == 0 && blockIdx.x == 0) {
        flags[0] = (ln1g_raw[0] == 0x3F800000u) ? 1 : 0;
        unsigned acc = 0;
        for (int j = 1; j < 32; j += 2) acc |= ei_raw[j];
        flags[1] = (acc == 0u) ? 1 : 0;
    }
}

struct Ptrs24 { const void* p[24]; };

#define CAST_TOTAL 1681171

__global__ __launch_bounds__(256) void cast_all(Ptrs24 ptrs, const int* __restrict__ flags,
                                                __hip_bfloat16* __restrict__ canon) {
    const int sizes[24] = {524288,131072,32768,256,65536,256,196608,768,65536,256,
                           256,256,262144,1024,262144,256,256,256,4096,16,
                           131072,512,1536,3};
    int i = blockIdx.x * 256 + threadIdx.x;
    if (i >= CAST_TOTAL) return;
    const int f32 = flags[0];
    int off = i, seg = 0;
    bool done = false;
#pragma unroll
    for (int s = 0; s < 24; s++) {
        if (!done) {
            if (off < sizes[s]) { seg = s; done = true; }
            else off -= sizes[s];
        }
    }
    float v = f32 ? ((const float*)ptrs.p[seg])[off]
                  : b2f(((const __hip_bfloat16*)ptrs.p[seg])[off]);
    canon[i] = f2b(v);
}

static __device__ __forceinline__ int ld_idx(const void* ei, int k, int i64) {
    return i64 ? (int)((const long long*)ei)[k] : ((const int*)ei)[k];
}

// ---------------------------------------------------------------- graph prep
__global__ __launch_bounds__(256) void deg_init_k(float* deg, int* cnt) {
    int i = blockIdx.x * 256 + threadIdx.x;
    if (i < N_NODES) { deg[i] = 1.0f; cnt[i] = 0; }   // self-loop weight 1
}

__global__ __launch_bounds__(256) void deg_scat_k(const void* __restrict__ ei,
                                                  const __hip_bfloat16* __restrict__ ew,
                                                  const int* __restrict__ flags,
                                                  float* deg, int* cnt) {
    int e = blockIdx.x * 256 + threadIdx.x;
    if (e < N_EDGES) {
        int d = ld_idx(ei, N_EDGES + e, flags[1]);
        atomicAdd(&deg[d], b2f(ew[e]));
        atomicAdd(&cnt[d], 1);
    }
}

// single block: dinv + exclusive scan of cnt -> rowptr, zero cnt for reuse as cursor
__global__ __launch_bounds__(256) void scan_k(const float* __restrict__ deg, float* dinv,
                                              int* cnt, int* rowptr) {
    __shared__ int ss[256];
    const int t = threadIdx.x;
    const int base = t * 16;
    int loc[16];
    int run = 0;
#pragma unroll
    for (int j = 0; j < 16; j++) { loc[j] = run; run += cnt[base + j]; }
    ss[t] = run;
    __syncthreads();
    for (int off = 1; off < 256; off <<= 1) {
        int v = (t >= off) ? ss[t - off] : 0;
        __syncthreads();
        ss[t] += v;
        __syncthreads();
    }
    int pre = (t == 0) ? 0 : ss[t - 1];
#pragma unroll
    for (int j = 0; j < 16; j++) rowptr[base + j] = pre + loc[j];
    if (t == 255) rowptr[N_NODES] = pre + run;
    for (int i = t; i < N_NODES; i += 256) {
        float dg = deg[i];
        dinv[i] = dg > 0.f ? rsqrtf(dg) : 0.f;
        cnt[i] = 0;
    }
}

__global__ __launch_bounds__(256) void fill_k(const void* __restrict__ ei,
                                              const __hip_bfloat16* __restrict__ ew,
                                              const int* __restrict__ flags,
                                              const float* __restrict__ dinv,
                                              const int* __restrict__ rowptr,
                                              int* cur, int* csrc, float* cw) {
    int e = blockIdx.x * 256 + threadIdx.x;
    if (e < N_EDGES) {
        int i64 = flags[1];
        int s = ld_idx(ei, e, i64), d = ld_idx(ei, N_EDGES + e, i64);
        int p = atomicAdd(&cur[d], 1);
        int slot = rowptr[d] + p;
        csrc[slot] = s;
        cw[slot] = dinv[s] * b2f(ew[e]) * dinv[d];
    }
}

// one block per dst node; thread c handles channel c (H=256)
template <bool RELU>
__global__ __launch_bounds__(256) void gcn_agg(const __hip_bfloat16* __restrict__ h,
                                               const float* __restrict__ dinv,
                                               const int* __restrict__ rowptr,
                                               const int* __restrict__ csrc,
                                               const float* __restrict__ cw,
                                               const __hip_bfloat16* __restrict__ bias,
                                               __hip_bfloat16* __restrict__ out) {
    const int n = blockIdx.x;
    const int c = threadIdx.x;
    const float di = dinv[n];
    float acc = di * di * b2f(h[(size_t)n * 256 + c]) + b2f(bias[c]);
    const int beg = rowptr[n], end = rowptr[n + 1];
    for (int p = beg; p < end; p++) {
        int s = csrc[p];
        float w = cw[p];
        acc = fmaf(w, b2f(h[(size_t)s * 256 + c]), acc);
    }
    if (RELU) acc = fmaxf(acc, 0.f);
    out[(size_t)n * 256 + c] = f2b(acc);
}

// ---------------------------------------------------------------- MFMA GEMM
// C[M,N] = act(A[M,K] @ B + bias). B is [K,N] (NN) or [N,K] (TRANSB => A@B^T).
template <bool TRANSB, bool BIAS, bool RELU>
__global__ __launch_bounds__(256) void gemm64(const __hip_bfloat16* __restrict__ A,
                                              const __hip_bfloat16* __restrict__ B,
                                              const __hip_bfloat16* __restrict__ bias,
                                              __hip_bfloat16* __restrict__ C,
                                              int K, int Nn) {
    __shared__ __align__(16) short As[64 * 40];   // [row][k], stride 40
    __shared__ __align__(16) short Bs[64 * 40];   // [n][k]
    const int t = threadIdx.x;
    const int m0 = blockIdx.y * 64, n0 = blockIdx.x * 64;
    const int lane = t & 63, w = t >> 6, li = lane & 15, g = lane >> 4;

    f32x4 acc[4];
#pragma unroll
    for (int i = 0; i < 4; i++) acc[i] = (f32x4){0.f, 0.f, 0.f, 0.f};

    const int arow = (t * 8) >> 5;       // 0..63
    const int acol = (t * 8) & 31;       // 0,8,16,24

    for (int k0 = 0; k0 < K; k0 += 32) {
        {
            uint4 v = *(const uint4*)((const ushort*)A + (size_t)(m0 + arow) * K + k0 + acol);
            *(uint4*)&As[arow * 40 + acol] = v;
        }
        if (TRANSB) {
            uint4 v = *(const uint4*)((const ushort*)B + (size_t)(n0 + arow) * K + k0 + acol);
            *(uint4*)&Bs[arow * 40 + acol] = v;
        } else {
            const int bk = t >> 3;            // 0..31
            const int bn = (t & 7) * 8;       // 0..56
            uint4 v = *(const uint4*)((const ushort*)B + (size_t)(k0 + bk) * Nn + n0 + bn);
            const short* sv = (const short*)&v;
#pragma unroll
            for (int j = 0; j < 8; j++) Bs[(bn + j) * 40 + bk] = sv[j];
        }
        __syncthreads();
        bf16x8 a = *(const bf16x8*)&As[(w * 16 + li) * 40 + g * 8];
#pragma unroll
        for (int nt = 0; nt < 4; nt++) {
            bf16x8 b = *(const bf16x8*)&Bs[(nt * 16 + li) * 40 + g * 8];
            acc[nt] = __builtin_amdgcn_mfma_f32_16x16x32_bf16(a, b, acc[nt], 0, 0, 0);
        }
        __syncthreads();
    }
#pragma unroll
    for (int nt = 0; nt < 4; nt++) {
        const int col = n0 + nt * 16 + li;
        const float bv = BIAS ? b2f(bias[col]) : 0.f;
#pragma unroll
        for (int r = 0; r < 4; r++) {
            const int row = m0 + w * 16 + g * 4 + r;
            float v = acc[nt][r] + bv;
            if (RELU) v = fmaxf(v, 0.f);
            C[(size_t)row * Nn + col] = f2b(v);
        }
    }
}

// ---------------------------------------------------------------- flash attention
__global__ __launch_bounds__(256) void attn64(const __hip_bfloat16* __restrict__ qkv,
                                              __hip_bfloat16* __restrict__ ctx) {
    __shared__ __align__(16) short Qs[64 * 72];
    __shared__ __align__(16) short Ks[64 * 72];
    __shared__ __align__(16) short Vt[64 * 72];   // [dim][key]
    __shared__ __align__(16) short Ps[64 * 72];
    const int t = threadIdx.x;
    const int h = blockIdx.y;
    const int q0 = blockIdx.x * 64;
    const int lane = t & 63, w = t >> 6, li = lane & 15, g = lane >> 4;

#pragma unroll
    for (int it = 0; it < 2; it++) {
        int idx = it * 256 + t;
        int r = idx >> 3, d = (idx & 7) * 8;
        uint4 v = *(const uint4*)((const ushort*)qkv + (size_t)(q0 + r) * 768 + h * 64 + d);
        *(uint4*)&Qs[r * 72 + d] = v;
    }

    f32x4 O[4];
#pragma unroll
    for (int i = 0; i < 4; i++) O[i] = (f32x4){0.f, 0.f, 0.f, 0.f};
    float m_run[4], l_run[4];
#pragma unroll
    for (int r = 0; r < 4; r++) { m_run[r] = -1e30f; l_run[r] = 0.f; }

    for (int j0 = 0; j0 < N_NODES; j0 += 64) {
#pragma unroll
        for (int it = 0; it < 2; it++) {
            int idx = it * 256 + t;
            int r = idx >> 3, d = (idx & 7) * 8;
            uint4 kv = *(const uint4*)((const ushort*)qkv + (size_t)(j0 + r) * 768 + 256 + h * 64 + d);
            *(uint4*)&Ks[r * 72 + d] = kv;
            uint4 vv = *(const uint4*)((const ushort*)qkv + (size_t)(j0 + r) * 768 + 512 + h * 64 + d);
            const short* sv = (const short*)&vv;
#pragma unroll
            for (int j = 0; j < 8; j++) Vt[(d + j) * 72 + r] = sv[j];
        }
        __syncthreads();

        f32x4 S[4];
#pragma unroll
        for (int i = 0; i < 4; i++) S[i] = (f32x4){0.f, 0.f, 0.f, 0.f};
#pragma unroll
        for (int kk = 0; kk < 64; kk += 32) {
            bf16x8 a = *(const bf16x8*)&Qs[(w * 16 + li) * 72 + kk + g * 8];
#pragma unroll
            for (int nt = 0; nt < 4; nt++) {
                bf16x8 b = *(const bf16x8*)&Ks[(nt * 16 + li) * 72 + kk + g * 8];
                S[nt] = __builtin_amdgcn_mfma_f32_16x16x32_bf16(a, b, S[nt], 0, 0, 0);
            }
        }

        float alpha[4];
#pragma unroll
        for (int r = 0; r < 4; r++) {
            float mx = -1e30f;
#pragma unroll
            for (int nt = 0; nt < 4; nt++) {
                S[nt][r] *= 0.125f;                 // 1/sqrt(HD)
                mx = fmaxf(mx, S[nt][r]);
            }
            mx = rmax16(mx);
            float mnew = fmaxf(m_run[r], mx);
            alpha[r] = __expf(m_run[r] - mnew);
            m_run[r] = mnew;
            float rs = 0.f;
#pragma unroll
            for (int nt = 0; nt < 4; nt++) {
                float p = __expf(S[nt][r] - mnew);
                S[nt][r] = p;
                rs += p;
            }
            rs = rsum16(rs);
            l_run[r] = l_run[r] * alpha[r] + rs;
        }
#pragma unroll
        for (int nt = 0; nt < 4; nt++)
#pragma unroll
            for (int r = 0; r < 4; r++) {
                Ps[(w * 16 + g * 4 + r) * 72 + nt * 16 + li] = f2bs(S[nt][r]);
                O[nt][r] *= alpha[r];
            }
        __syncthreads();

#pragma unroll
        for (int kk = 0; kk < 64; kk += 32) {
            bf16x8 a = *(const bf16x8*)&Ps[(w * 16 + li) * 72 + kk + g * 8];
#pragma unroll
            for (int nt = 0; nt < 4; nt++) {
                bf16x8 b = *(const bf16x8*)&Vt[(nt * 16 + li) * 72 + kk + g * 8];
                O[nt] = __builtin_amdgcn_mfma_f32_16x16x32_bf16(a, b, O[nt], 0, 0, 0);
            }
        }
        __syncthreads();
    }
#pragma unroll
    for (int nt = 0; nt < 4; nt++)
#pragma unroll
        for (int r = 0; r < 4; r++) {
            const int row = q0 + w * 16 + g * 4 + r;
            ctx[(size_t)row * 256 + h * 64 + nt * 16 + li] = f2b(O[nt][r] / l_run[r]);
        }
}

// ---------------------------------------------------------------- layernorm (+res)
template <bool ADDC>
__global__ __launch_bounds__(256) void ln256(const __hip_bfloat16* __restrict__ A,
                                             const __hip_bfloat16* __restrict__ Bv,
                                             const __hip_bfloat16* __restrict__ gw,
                                             const __hip_bfloat16* __restrict__ bw,
                                             const __hip_bfloat16* __restrict__ Cadd,
                                             __hip_bfloat16* __restrict__ out) {
    __shared__ float red[8];
    const int row = blockIdx.x, c = threadIdx.x;
    const size_t o = (size_t)row * 256 + c;
    float x = b2f(A[o]) + b2f(Bv[o]);
    float s = x;
#pragma unroll
    for (int m = 1; m < 64; m <<= 1) s += __shfl_xor(s, m);
    const int wv = c >> 6;
    if ((c & 63) == 0) red[wv] = s;
    __syncthreads();
    float mu = (red[0] + red[1] + red[2] + red[3]) * (1.f / 256.f);
    float d = x - mu;
    float s2 = d * d;
#pragma unroll
    for (int m = 1; m < 64; m <<= 1) s2 += __shfl_xor(s2, m);
    if ((c & 63) == 0) red[4 + wv] = s2;
    __syncthreads();
    float var = (red[4] + red[5] + red[6] + red[7]) * (1.f / 256.f);
    float y = d * rsqrtf(var + 1e-5f) * b2f(gw[c]) + b2f(bw[c]);
    if (ADDC) y += b2f(Cadd[o]);
    out[o] = f2b(y);
}

// ---------------------------------------------------------------- heads
__global__ __launch_bounds__(256) void cls16(const __hip_bfloat16* __restrict__ xf,
                                             const __hip_bfloat16* __restrict__ W,
                                             const __hip_bfloat16* __restrict__ b,
                                             const int* __restrict__ flags,
                                             void* __restrict__ out) {
    __shared__ float Ws[256 * 16];
    __shared__ float bs[16];
    const int t = threadIdx.x;
    for (int i = t; i < 4096; i += 256) Ws[i] = b2f(W[i]);
    if (t < 16) bs[t] = b2f(b[t]);
    __syncthreads();
    const int c = t & 15, rl = t >> 4;
    const int row = blockIdx.x * 16 + rl;
    const __hip_bfloat16* xr = xf + (size_t)row * 256;
    float acc = bs[c];
    for (int k = 0; k < 256; k++) acc = fmaf(b2f(xr[k]), Ws[k * 16 + c], acc);
    float mx = rmax16(acc);
    float se = rsum16(__expf(acc - mx));
    float v = acc - mx - __logf(se);
    const size_t oidx = (size_t)row * 16 + c;
    if (flags[0]) ((float*)out)[oidx] = v;
    else          ((__hip_bfloat16*)out)[oidx] = f2b(v);
}

__global__ __launch_bounds__(256) void reco3(const __hip_bfloat16* __restrict__ hid,
                                             const __hip_bfloat16* __restrict__ W,
                                             const __hip_bfloat16* __restrict__ b,
                                             const int* __restrict__ flags,
                                             void* __restrict__ out) {
    __shared__ float Ws[512 * 3];
    const int t = threadIdx.x;
    for (int i = t; i < 1536; i += 256) Ws[i] = b2f(W[i]);
    __syncthreads();
    const int c = t & 3, rl = t >> 2;
    const int row = blockIdx.x * 64 + rl;
    if (c < 3) {
        float acc = b2f(b[c]);
        const __hip_bfloat16* hr = hid + (size_t)row * 512;
        for (int k = 0; k < 512; k++) acc = fmaf(b2f(hr[k]), Ws[k * 3 + c], acc);
        float v = 1.f / (1.f + __expf(-acc));
        const size_t oidx = (size_t)(N_NODES * 16) + (size_t)row * 3 + c;
        if (flags[0]) ((float*)out)[oidx] = v;
        else          ((__hip_bfloat16*)out)[oidx] = f2b(v);
    }
}

// ---------------------------------------------------------------- launch
extern "C" void kernel_launch(void* const* d_in, const int* in_sizes, int n_in,
                              void* d_out, int out_size, void* d_ws, size_t ws_size,
                              hipStream_t stream) {
    char* ws = (char*)d_ws;
    int*   flags  = (int*)(ws + 0);                        // 16 B
    __hip_bfloat16* canon = (__hip_bfloat16*)(ws + 256);   // 1681171 elems
    float* deg    = (float*)(ws + 3362816);
    int*   cnt    = (int*)  (ws + 3379200);
    int*   rowptr = (int*)  (ws + 3395584);
    float* dinv   = (float*)(ws + 3412224);
    int*   csrc   = (int*)  (ws + 3428608);
    float* cw     = (float*)(ws + 3952896);
    __hip_bfloat16* h     = (__hip_bfloat16*)(ws + 4477184);
    __hip_bfloat16* x1    = (__hip_bfloat16*)(ws + 6574336);
    __hip_bfloat16* xloc  = (__hip_bfloat16*)(ws + 8671488);
    __hip_bfloat16* big   = (__hip_bfloat16*)(ws + 10768640);  // 8 MB: qkv -> f1 -> hid
    __hip_bfloat16* ctxp  = (__hip_bfloat16*)(ws + 19157248);
    __hip_bfloat16* attno = (__hip_bfloat16*)(ws + 21254400);
    __hip_bfloat16* y1    = (__hip_bfloat16*)(ws + 23351552);
    __hip_bfloat16* xfin  = (__hip_bfloat16*)(ws + 25448704);

    // canonical bf16 tensor offsets (elements)
    const __hip_bfloat16* xc    = canon + 0;
    const __hip_bfloat16* eac   = canon + 524288;
    const __hip_bfloat16* Wg1   = canon + 655360;
    const __hip_bfloat16* bg1   = canon + 688128;
    const __hip_bfloat16* Wg2   = canon + 688384;
    const __hip_bfloat16* bg2   = canon + 753920;
    const __hip_bfloat16* ipw   = canon + 754176;
    const __hip_bfloat16* ipb   = canon + 950784;
    const __hip_bfloat16* opw   = canon + 951552;
    const __hip_bfloat16* opb   = canon + 1017088;
    const __hip_bfloat16* ln1g  = canon + 1017344;
    const __hip_bfloat16* ln1b  = canon + 1017600;
    const __hip_bfloat16* fw1   = canon + 1017856;
    const __hip_bfloat16* fb1   = canon + 1280000;
    const __hip_bfloat16* fw2   = canon + 1281024;
    const __hip_bfloat16* fb2   = canon + 1543168;
    const __hip_bfloat16* ln2g  = canon + 1543424;
    const __hip_bfloat16* ln2b  = canon + 1543680;
    const __hip_bfloat16* Wcls  = canon + 1543936;
    const __hip_bfloat16* bcls  = canon + 1548032;
    const __hip_bfloat16* Wd1   = canon + 1548048;
    const __hip_bfloat16* bd1   = canon + 1679120;
    const __hip_bfloat16* Wd2   = canon + 1679632;
    const __hip_bfloat16* bd2   = canon + 1681168;

    const void* ei = d_in[1];

    Ptrs24 pt;
    {
        const int map[24] = {0,2,3,4,5,6,7,8,9,10,11,12,13,14,15,16,17,18,19,20,21,22,23,24};
        for (int i = 0; i < 24; i++) pt.p[i] = d_in[map[i]];
    }

    const dim3 b256(256);

    probe_k<<<1, 64, 0, stream>>>((const unsigned*)d_in[11], (const unsigned*)d_in[1], flags);
    cast_all<<<(CAST_TOTAL + 255) / 256, b256, 0, stream>>>(pt, flags, canon);

    // graph prep (once, reused by both GCN layers)
    deg_init_k<<<16, b256, 0, stream>>>(deg, cnt);
    deg_scat_k<<<512, b256, 0, stream>>>(ei, eac, flags, deg, cnt);
    scan_k<<<1, b256, 0, stream>>>(deg, dinv, cnt, rowptr);
    fill_k<<<512, b256, 0, stream>>>(ei, eac, flags, dinv, rowptr, cnt, csrc, cw);

    // GCN1: h = x @ W_gcn1 ; x1 = relu(agg(h) + b1)
    gemm64<false, false, false><<<dim3(4, 64), b256, 0, stream>>>(xc, Wg1, nullptr, h, 128, 256);
    gcn_agg<true><<<4096, b256, 0, stream>>>(h, dinv, rowptr, csrc, cw, bg1, x1);
    // GCN2
    gemm64<false, false, false><<<dim3(4, 64), b256, 0, stream>>>(x1, Wg2, nullptr, h, 256, 256);
    gcn_agg<false><<<4096, b256, 0, stream>>>(h, dinv, rowptr, csrc, cw, bg2, xloc);

    // transformer
    gemm64<true, true, false><<<dim3(12, 64), b256, 0, stream>>>(xloc, ipw, ipb, big, 256, 768);  // qkv
    attn64<<<dim3(64, 4), b256, 0, stream>>>(big, ctxp);
    gemm64<true, true, false><<<dim3(4, 64), b256, 0, stream>>>(ctxp, opw, opb, attno, 256, 256);
    ln256<false><<<4096, b256, 0, stream>>>(xloc, attno, ln1g, ln1b, nullptr, y1);
    gemm64<false, true, true><<<dim3(16, 64), b256, 0, stream>>>(y1, fw1, fb1, big, 256, 1024);   // f1
    gemm64<false, true, false><<<dim3(4, 64), b256, 0, stream>>>(big, fw2, fb2, ctxp, 1024, 256); // f2
    ln256<true><<<4096, b256, 0, stream>>>(y1, ctxp, ln2g, ln2b, xloc, xfin);  // xfin = xloc + ln2(...)

    // heads
    cls16<<<256, b256, 0, stream>>>(xfin, Wcls, bcls, flags, d_out);
    gemm64<false, true, true><<<dim3(8, 64), b256, 0, stream>>>(xfin, Wd1, bd1, big, 256, 512);   // hid
    reco3<<<64, b256, 0, stream>>>(big, Wd2, bd2, flags, d_out);
}

// Round 3
// 330.411 us; speedup vs baseline: 1.2987x; 1.2987x over previous
//
#include <hip/hip_runtime.h>
#include <hip/hip_bf16.h>

#define N_NODES 4096
#define N_EDGES 131072
#define KSPLIT 4

typedef short bf16x8 __attribute__((ext_vector_type(8)));
typedef float f32x4  __attribute__((ext_vector_type(4)));

static __device__ __forceinline__ float b2f(__hip_bfloat16 x) { return __bfloat162float(x); }
static __device__ __forceinline__ __hip_bfloat16 f2b(float x) { return __float2bfloat16(x); }
static __device__ __forceinline__ short f2bs(float x) {
    __hip_bfloat16 h = __float2bfloat16(x);
    return *reinterpret_cast<short*>(&h);
}
static __device__ __forceinline__ float us2f(ushort u) {
    union { unsigned i; float f; } x; x.i = ((unsigned)u) << 16; return x.f;
}

static __device__ __forceinline__ float rmax16(float v) {
    v = fmaxf(v, __shfl_xor(v, 1));
    v = fmaxf(v, __shfl_xor(v, 2));
    v = fmaxf(v, __shfl_xor(v, 4));
    v = fmaxf(v, __shfl_xor(v, 8));
    return v;
}
static __device__ __forceinline__ float rsum16(float v) {
    v += __shfl_xor(v, 1);
    v += __shfl_xor(v, 2);
    v += __shfl_xor(v, 4);
    v += __shfl_xor(v, 8);
    return v;
}

// ------------------------------------------------------------ dtype probe
__global__ void probe_k(const unsigned* __restrict__ ln1g_raw,
                        const unsigned* __restrict__ ei_raw, int* flags) {
    if (threadIdx.x == 0 && blockIdx.x == 0) {
        flags[0] = (ln1g_raw[0] == 0x3F800000u) ? 1 : 0;
        unsigned acc = 0;
        for (int j = 1; j < 32; j += 2) acc |= ei_raw[j];
        flags[1] = (acc == 0u) ? 1 : 0;
    }
}

struct Ptrs24 { const void* p[24]; };

#define CAST_TOTAL 1681171

// casts all float tensors to canonical bf16; transposes the 5 NN-layout
// weights (segs 2,4,12,14,20) so every GEMM can use the vectorized B^T path.
__global__ __launch_bounds__(256) void cast_all(Ptrs24 ptrs, const int* __restrict__ flags,
                                                __hip_bfloat16* __restrict__ canon) {
    const int sizes[24] = {524288,131072,32768,256,65536,256,196608,768,65536,256,
                           256,256,262144,1024,262144,256,256,256,4096,16,
                           131072,512,1536,3};
    int i = blockIdx.x * 256 + threadIdx.x;
    if (i >= CAST_TOTAL) return;
    const int f32 = flags[0];
    int off = i, seg = 0, base = 0;
    bool done = false;
#pragma unroll
    for (int s = 0; s < 24; s++) {
        if (!done) {
            if (off < sizes[s]) { seg = s; done = true; }
            else { off -= sizes[s]; base += sizes[s]; }
        }
    }
    float v = f32 ? ((const float*)ptrs.p[seg])[off]
                  : b2f(((const __hip_bfloat16*)ptrs.p[seg])[off]);
    int dst = off;
    if (seg == 2)       dst = (off & 255)  * 128  + (off >> 8);   // Wg1 (128,256)->T
    else if (seg == 4)  dst = (off & 255)  * 256  + (off >> 8);   // Wg2 (256,256)->T
    else if (seg == 12) dst = (off & 1023) * 256  + (off >> 10);  // fw1 (256,1024)->T
    else if (seg == 14) dst = (off & 255)  * 1024 + (off >> 8);   // fw2 (1024,256)->T
    else if (seg == 20) dst = (off & 511)  * 256  + (off >> 9);   // Wd1 (256,512)->T
    canon[base + dst] = f2b(v);
}

static __device__ __forceinline__ int ld_idx(const void* ei, int k, int i64) {
    return i64 ? (int)((const long long*)ei)[k] : ((const int*)ei)[k];
}

// ---------------------------------------------------------------- graph prep
__global__ __launch_bounds__(256) void deg_init_k(float* deg, int* cnt) {
    int i = blockIdx.x * 256 + threadIdx.x;
    if (i < N_NODES) { deg[i] = 1.0f; cnt[i] = 0; }
}

__global__ __launch_bounds__(256) void deg_scat_k(const void* __restrict__ ei,
                                                  const __hip_bfloat16* __restrict__ ew,
                                                  const int* __restrict__ flags,
                                                  float* deg, int* cnt) {
    int e = blockIdx.x * 256 + threadIdx.x;
    if (e < N_EDGES) {
        int d = ld_idx(ei, N_EDGES + e, flags[1]);
        atomicAdd(&deg[d], b2f(ew[e]));
        atomicAdd(&cnt[d], 1);
    }
}

__global__ __launch_bounds__(256) void scan_k(const float* __restrict__ deg, float* dinv,
                                              int* cnt, int* rowptr) {
    __shared__ int ss[256];
    const int t = threadIdx.x;
    const int base = t * 16;
    int loc[16];
    int run = 0;
#pragma unroll
    for (int j = 0; j < 16; j++) { loc[j] = run; run += cnt[base + j]; }
    ss[t] = run;
    __syncthreads();
    for (int off = 1; off < 256; off <<= 1) {
        int v = (t >= off) ? ss[t - off] : 0;
        __syncthreads();
        ss[t] += v;
        __syncthreads();
    }
    int pre = (t == 0) ? 0 : ss[t - 1];
#pragma unroll
    for (int j = 0; j < 16; j++) rowptr[base + j] = pre + loc[j];
    if (t == 255) rowptr[N_NODES] = pre + run;
    for (int i = t; i < N_NODES; i += 256) {
        float dg = deg[i];
        dinv[i] = dg > 0.f ? rsqrtf(dg) : 0.f;
        cnt[i] = 0;
    }
}

__global__ __launch_bounds__(256) void fill_k(const void* __restrict__ ei,
                                              const __hip_bfloat16* __restrict__ ew,
                                              const int* __restrict__ flags,
                                              const float* __restrict__ dinv,
                                              const int* __restrict__ rowptr,
                                              int* cur, int* csrc, float* cw) {
    int e = blockIdx.x * 256 + threadIdx.x;
    if (e < N_EDGES) {
        int i64 = flags[1];
        int s = ld_idx(ei, e, i64), d = ld_idx(ei, N_EDGES + e, i64);
        int p = atomicAdd(&cur[d], 1);
        int slot = rowptr[d] + p;
        csrc[slot] = s;
        cw[slot] = dinv[s] * b2f(ew[e]) * dinv[d];
    }
}

// wave per node, 4 channels/lane (8B vector loads), 4x edge unroll
template <bool RELU>
__global__ __launch_bounds__(256) void gcn_agg(const __hip_bfloat16* __restrict__ hf,
                                               const float* __restrict__ dinv,
                                               const int* __restrict__ rowptr,
                                               const int* __restrict__ csrc,
                                               const float* __restrict__ cw,
                                               const __hip_bfloat16* __restrict__ bias,
                                               __hip_bfloat16* __restrict__ out) {
    const int t = threadIdx.x;
    const int n = blockIdx.x * 4 + (t >> 6);
    const int c0 = (t & 63) * 4;
    const ushort* hp = (const ushort*)hf;
    const float di = dinv[n];
    float acc[4];
    {
        ushort4 own = *(const ushort4*)(hp + (size_t)n * 256 + c0);
        ushort4 bv  = *(const ushort4*)((const ushort*)bias + c0);
        const float dii = di * di;
        acc[0] = fmaf(dii, us2f(own.x), us2f(bv.x));
        acc[1] = fmaf(dii, us2f(own.y), us2f(bv.y));
        acc[2] = fmaf(dii, us2f(own.z), us2f(bv.z));
        acc[3] = fmaf(dii, us2f(own.w), us2f(bv.w));
    }
    int p = rowptr[n];
    const int end = rowptr[n + 1];
    for (; p + 4 <= end; p += 4) {
        int s0 = csrc[p], s1 = csrc[p + 1], s2 = csrc[p + 2], s3 = csrc[p + 3];
        float w0 = cw[p], w1 = cw[p + 1], w2 = cw[p + 2], w3 = cw[p + 3];
        ushort4 v0 = *(const ushort4*)(hp + (size_t)s0 * 256 + c0);
        ushort4 v1 = *(const ushort4*)(hp + (size_t)s1 * 256 + c0);
        ushort4 v2 = *(const ushort4*)(hp + (size_t)s2 * 256 + c0);
        ushort4 v3 = *(const ushort4*)(hp + (size_t)s3 * 256 + c0);
        acc[0] = fmaf(w0, us2f(v0.x), acc[0]); acc[1] = fmaf(w0, us2f(v0.y), acc[1]);
        acc[2] = fmaf(w0, us2f(v0.z), acc[2]); acc[3] = fmaf(w0, us2f(v0.w), acc[3]);
        acc[0] = fmaf(w1, us2f(v1.x), acc[0]); acc[1] = fmaf(w1, us2f(v1.y), acc[1]);
        acc[2] = fmaf(w1, us2f(v1.z), acc[2]); acc[3] = fmaf(w1, us2f(v1.w), acc[3]);
        acc[0] = fmaf(w2, us2f(v2.x), acc[0]); acc[1] = fmaf(w2, us2f(v2.y), acc[1]);
        acc[2] = fmaf(w2, us2f(v2.z), acc[2]); acc[3] = fmaf(w2, us2f(v2.w), acc[3]);
        acc[0] = fmaf(w3, us2f(v3.x), acc[0]); acc[1] = fmaf(w3, us2f(v3.y), acc[1]);
        acc[2] = fmaf(w3, us2f(v3.z), acc[2]); acc[3] = fmaf(w3, us2f(v3.w), acc[3]);
    }
    for (; p < end; p++) {
        int s = csrc[p];
        float wgt = cw[p];
        ushort4 v = *(const ushort4*)(hp + (size_t)s * 256 + c0);
        acc[0] = fmaf(wgt, us2f(v.x), acc[0]); acc[1] = fmaf(wgt, us2f(v.y), acc[1]);
        acc[2] = fmaf(wgt, us2f(v.z), acc[2]); acc[3] = fmaf(wgt, us2f(v.w), acc[3]);
    }
    if (RELU) {
#pragma unroll
        for (int j = 0; j < 4; j++) acc[j] = fmaxf(acc[j], 0.f);
    }
    ushort4 o;
    o.x = (ushort)f2bs(acc[0]); o.y = (ushort)f2bs(acc[1]);
    o.z = (ushort)f2bs(acc[2]); o.w = (ushort)f2bs(acc[3]);
    *(ushort4*)((ushort*)out + (size_t)n * 256 + c0) = o;
}

// ---------------------------------------------------------------- MFMA GEMM (B^T only)
// C[M,N] = act(A[M,K] @ Bt^T + bias), Bt is [N,K] row-major.
template <bool BIAS, bool RELU>
__global__ __launch_bounds__(256) void gemm64(const __hip_bfloat16* __restrict__ A,
                                              const __hip_bfloat16* __restrict__ Bt,
                                              const __hip_bfloat16* __restrict__ bias,
                                              __hip_bfloat16* __restrict__ C,
                                              int K, int Nn) {
    __shared__ __align__(16) short As[64 * 40];
    __shared__ __align__(16) short Bs[64 * 40];
    const int t = threadIdx.x;
    const int m0 = blockIdx.y * 64, n0 = blockIdx.x * 64;
    const int lane = t & 63, w = t >> 6, li = lane & 15, g = lane >> 4;

    f32x4 acc[4];
#pragma unroll
    for (int i = 0; i < 4; i++) acc[i] = (f32x4){0.f, 0.f, 0.f, 0.f};

    const int arow = (t * 8) >> 5;
    const int acol = (t * 8) & 31;

    for (int k0 = 0; k0 < K; k0 += 32) {
        {
            uint4 v = *(const uint4*)((const ushort*)A + (size_t)(m0 + arow) * K + k0 + acol);
            *(uint4*)&As[arow * 40 + acol] = v;
            uint4 b = *(const uint4*)((const ushort*)Bt + (size_t)(n0 + arow) * K + k0 + acol);
            *(uint4*)&Bs[arow * 40 + acol] = b;
        }
        __syncthreads();
        bf16x8 a = *(const bf16x8*)&As[(w * 16 + li) * 40 + g * 8];
#pragma unroll
        for (int nt = 0; nt < 4; nt++) {
            bf16x8 b = *(const bf16x8*)&Bs[(nt * 16 + li) * 40 + g * 8];
            acc[nt] = __builtin_amdgcn_mfma_f32_16x16x32_bf16(a, b, acc[nt], 0, 0, 0);
        }
        __syncthreads();
    }
#pragma unroll
    for (int nt = 0; nt < 4; nt++) {
        const int col = n0 + nt * 16 + li;
        const float bv = BIAS ? b2f(bias[col]) : 0.f;
#pragma unroll
        for (int r = 0; r < 4; r++) {
            const int row = m0 + w * 16 + g * 4 + r;
            float v = acc[nt][r] + bv;
            if (RELU) v = fmaxf(v, 0.f);
            C[(size_t)row * Nn + col] = f2b(v);
        }
    }
}

// ---------------------------------------------------------------- flash attention, split-K
// grid (64 q-tiles, 4 heads, KSPLIT); each block covers 1024 keys, writes f32 partials.
__global__ __launch_bounds__(256) void attn_part(const __hip_bfloat16* __restrict__ qkv,
                                                 float* __restrict__ Opart,
                                                 float2* __restrict__ MLpart) {
    __shared__ __align__(16) short Qs[64 * 72];
    __shared__ __align__(16) short Ks[64 * 72];
    __shared__ __align__(16) short Vt[64 * 72];   // [dim][key]
    __shared__ __align__(16) short Ps[64 * 72];
    const int t = threadIdx.x;
    const int h = blockIdx.y;
    const int q0 = blockIdx.x * 64;
    const int kz = blockIdx.z;
    const int lane = t & 63, w = t >> 6, li = lane & 15, g = lane >> 4;

#pragma unroll
    for (int it = 0; it < 2; it++) {
        int idx = it * 256 + t;
        int r = idx >> 3, d = (idx & 7) * 8;
        uint4 v = *(const uint4*)((const ushort*)qkv + (size_t)(q0 + r) * 768 + h * 64 + d);
        *(uint4*)&Qs[r * 72 + d] = v;
    }

    f32x4 O[4];
#pragma unroll
    for (int i = 0; i < 4; i++) O[i] = (f32x4){0.f, 0.f, 0.f, 0.f};
    float m_run[4], l_run[4];
#pragma unroll
    for (int r = 0; r < 4; r++) { m_run[r] = -1e30f; l_run[r] = 0.f; }

    const int jbeg = kz * 1024;
    for (int j0 = jbeg; j0 < jbeg + 1024; j0 += 64) {
        // K stage: b128 stores, uniform bank spread
#pragma unroll
        for (int it = 0; it < 2; it++) {
            int idx = it * 256 + t;
            int r = idx >> 3, d = (idx & 7) * 8;
            uint4 kv = *(const uint4*)((const ushort*)qkv + (size_t)(j0 + r) * 768 + 256 + h * 64 + d);
            *(uint4*)&Ks[r * 72 + d] = kv;
        }
        // V transpose stage: lane owns one key column -> bank = j*4 + lane/2 (2-way, free)
#pragma unroll
        for (int it = 0; it < 2; it++) {
            int dblk = it * 4 + w;
            uint4 vv = *(const uint4*)((const ushort*)qkv + (size_t)(j0 + lane) * 768 + 512 + h * 64 + dblk * 8);
            const short* sv = (const short*)&vv;
#pragma unroll
            for (int j = 0; j < 8; j++) Vt[(dblk * 8 + j) * 72 + lane] = sv[j];
        }
        __syncthreads();

        f32x4 S[4];
#pragma unroll
        for (int i = 0; i < 4; i++) S[i] = (f32x4){0.f, 0.f, 0.f, 0.f};
#pragma unroll
        for (int kk = 0; kk < 64; kk += 32) {
            bf16x8 a = *(const bf16x8*)&Qs[(w * 16 + li) * 72 + kk + g * 8];
#pragma unroll
            for (int nt = 0; nt < 4; nt++) {
                bf16x8 b = *(const bf16x8*)&Ks[(nt * 16 + li) * 72 + kk + g * 8];
                S[nt] = __builtin_amdgcn_mfma_f32_16x16x32_bf16(a, b, S[nt], 0, 0, 0);
            }
        }

        float alpha[4];
#pragma unroll
        for (int r = 0; r < 4; r++) {
            float mx = -1e30f;
#pragma unroll
            for (int nt = 0; nt < 4; nt++) {
                S[nt][r] *= 0.125f;
                mx = fmaxf(mx, S[nt][r]);
            }
            mx = rmax16(mx);
            float mnew = fmaxf(m_run[r], mx);
            alpha[r] = __expf(m_run[r] - mnew);
            m_run[r] = mnew;
            float rs = 0.f;
#pragma unroll
            for (int nt = 0; nt < 4; nt++) {
                float p = __expf(S[nt][r] - mnew);
                S[nt][r] = p;
                rs += p;
            }
            rs = rsum16(rs);
            l_run[r] = l_run[r] * alpha[r] + rs;
        }
#pragma unroll
        for (int nt = 0; nt < 4; nt++)
#pragma unroll
            for (int r = 0; r < 4; r++) {
                Ps[(w * 16 + g * 4 + r) * 72 + nt * 16 + li] = f2bs(S[nt][r]);
                O[nt][r] *= alpha[r];
            }
        __syncthreads();

#pragma unroll
        for (int kk = 0; kk < 64; kk += 32) {
            bf16x8 a = *(const bf16x8*)&Ps[(w * 16 + li) * 72 + kk + g * 8];
#pragma unroll
            for (int nt = 0; nt < 4; nt++) {
                bf16x8 b = *(const bf16x8*)&Vt[(nt * 16 + li) * 72 + kk + g * 8];
                O[nt] = __builtin_amdgcn_mfma_f32_16x16x32_bf16(a, b, O[nt], 0, 0, 0);
            }
        }
        __syncthreads();
    }

    const int hb = kz * 4 + h;
#pragma unroll
    for (int nt = 0; nt < 4; nt++)
#pragma unroll
        for (int r = 0; r < 4; r++) {
            int lr = w * 16 + g * 4 + r;
            Opart[((size_t)hb * 4096 + q0 + lr) * 64 + nt * 16 + li] = O[nt][r];
        }
    if (li == 0) {
#pragma unroll
        for (int r = 0; r < 4; r++) {
            int lr = w * 16 + g * 4 + r;
            MLpart[(size_t)hb * 4096 + q0 + lr] = make_float2(m_run[r], l_run[r]);
        }
    }
}

// combine: grid (64, 4), block 256; thread = (row, 16-dim group)
__global__ __launch_bounds__(256) void attn_comb(const float* __restrict__ Opart,
                                                 const float2* __restrict__ MLpart,
                                                 __hip_bfloat16* __restrict__ ctx) {
    const int t = threadIdx.x;
    const int h = blockIdx.y;
    const int row = blockIdx.x * 64 + (t >> 2);
    const int d0 = (t & 3) * 16;
    float m[KSPLIT], l[KSPLIT];
    float M = -1e30f;
#pragma unroll
    for (int s = 0; s < KSPLIT; s++) {
        float2 ml = MLpart[(size_t)(s * 4 + h) * 4096 + row];
        m[s] = ml.x; l[s] = ml.y;
        M = fmaxf(M, m[s]);
    }
    float L = 0.f, wgt[KSPLIT];
#pragma unroll
    for (int s = 0; s < KSPLIT; s++) { wgt[s] = __expf(m[s] - M); L += l[s] * wgt[s]; }
    const float inv = 1.f / L;
    float o[16];
#pragma unroll
    for (int j = 0; j < 16; j++) o[j] = 0.f;
#pragma unroll
    for (int s = 0; s < KSPLIT; s++) {
        const float* base = Opart + ((size_t)(s * 4 + h) * 4096 + row) * 64 + d0;
#pragma unroll
        for (int q = 0; q < 4; q++) {
            f32x4 v = *(const f32x4*)(base + q * 4);
#pragma unroll
            for (int j = 0; j < 4; j++) o[q * 4 + j] = fmaf(wgt[s], v[j], o[q * 4 + j]);
        }
    }
    ushort pk[16];
#pragma unroll
    for (int j = 0; j < 16; j++) pk[j] = (ushort)f2bs(o[j] * inv);
    ushort* dst = (ushort*)ctx + (size_t)row * 256 + h * 64 + d0;
    *(uint4*)dst = *(uint4*)pk;
    *(uint4*)(dst + 8) = *(uint4*)(pk + 8);
}

// ---------------------------------------------------------------- layernorm (+res)
template <bool ADDC>
__global__ __launch_bounds__(256) void ln256(const __hip_bfloat16* __restrict__ A,
                                             const __hip_bfloat16* __restrict__ Bv,
                                             const __hip_bfloat16* __restrict__ gw,
                                             const __hip_bfloat16* __restrict__ bw,
                                             const __hip_bfloat16* __restrict__ Cadd,
                                             __hip_bfloat16* __restrict__ out) {
    __shared__ float red[8];
    const int row = blockIdx.x, c = threadIdx.x;
    const size_t o = (size_t)row * 256 + c;
    float x = b2f(A[o]) + b2f(Bv[o]);
    float s = x;
#pragma unroll
    for (int m = 1; m < 64; m <<= 1) s += __shfl_xor(s, m);
    const int wv = c >> 6;
    if ((c & 63) == 0) red[wv] = s;
    __syncthreads();
    float mu = (red[0] + red[1] + red[2] + red[3]) * (1.f / 256.f);
    float d = x - mu;
    float s2 = d * d;
#pragma unroll
    for (int m = 1; m < 64; m <<= 1) s2 += __shfl_xor(s2, m);
    if ((c & 63) == 0) red[4 + wv] = s2;
    __syncthreads();
    float var = (red[4] + red[5] + red[6] + red[7]) * (1.f / 256.f);
    float y = d * rsqrtf(var + 1e-5f) * b2f(gw[c]) + b2f(bw[c]);
    if (ADDC) y += b2f(Cadd[o]);
    out[o] = f2b(y);
}

// ---------------------------------------------------------------- heads
__global__ __launch_bounds__(256) void cls16(const __hip_bfloat16* __restrict__ xf,
                                             const __hip_bfloat16* __restrict__ W,
                                             const __hip_bfloat16* __restrict__ b,
                                             const int* __restrict__ flags,
                                             void* __restrict__ out) {
    __shared__ float Ws[256 * 16];
    __shared__ float bs[16];
    const int t = threadIdx.x;
    for (int i = t; i < 4096; i += 256) Ws[i] = b2f(W[i]);
    if (t < 16) bs[t] = b2f(b[t]);
    __syncthreads();
    const int c = t & 15, rl = t >> 4;
    const int row = blockIdx.x * 16 + rl;
    const ushort* xr = (const ushort*)xf + (size_t)row * 256;
    float acc = bs[c];
    for (int k0 = 0; k0 < 256; k0 += 8) {
        uint4 v = *(const uint4*)(xr + k0);
        const ushort* sv = (const ushort*)&v;
#pragma unroll
        for (int j = 0; j < 8; j++) acc = fmaf(us2f(sv[j]), Ws[(k0 + j) * 16 + c], acc);
    }
    float mx = rmax16(acc);
    float se = rsum16(__expf(acc - mx));
    float v = acc - mx - __logf(se);
    const size_t oidx = (size_t)row * 16 + c;
    if (flags[0]) ((float*)out)[oidx] = v;
    else          ((__hip_bfloat16*)out)[oidx] = f2b(v);
}

__global__ __launch_bounds__(256) void reco3(const __hip_bfloat16* __restrict__ hid,
                                             const __hip_bfloat16* __restrict__ W,
                                             const __hip_bfloat16* __restrict__ b,
                                             const int* __restrict__ flags,
                                             void* __restrict__ out) {
    __shared__ float Ws[512 * 3];
    const int t = threadIdx.x;
    for (int i = t; i < 1536; i += 256) Ws[i] = b2f(W[i]);
    __syncthreads();
    const int c = t & 3, rl = t >> 2;
    const int row = blockIdx.x * 64 + rl;
    if (c < 3) {
        float acc = b2f(b[c]);
        const ushort* hr = (const ushort*)hid + (size_t)row * 512;
        for (int k0 = 0; k0 < 512; k0 += 8) {
            uint4 v = *(const uint4*)(hr + k0);
            const ushort* sv = (const ushort*)&v;
#pragma unroll
            for (int j = 0; j < 8; j++) acc = fmaf(us2f(sv[j]), Ws[(k0 + j) * 3 + c], acc);
        }
        float v = 1.f / (1.f + __expf(-acc));
        const size_t oidx = (size_t)(N_NODES * 16) + (size_t)row * 3 + c;
        if (flags[0]) ((float*)out)[oidx] = v;
        else          ((__hip_bfloat16*)out)[oidx] = f2b(v);
    }
}

// ---------------------------------------------------------------- launch
extern "C" void kernel_launch(void* const* d_in, const int* in_sizes, int n_in,
                              void* d_out, int out_size, void* d_ws, size_t ws_size,
                              hipStream_t stream) {
    char* ws = (char*)d_ws;
    int*   flags  = (int*)(ws + 0);
    __hip_bfloat16* canon = (__hip_bfloat16*)(ws + 256);
    float* deg    = (float*)(ws + 3362816);
    int*   cnt    = (int*)  (ws + 3379200);
    int*   rowptr = (int*)  (ws + 3395584);
    float* dinv   = (float*)(ws + 3412224);
    int*   csrc   = (int*)  (ws + 3428608);
    float* cw     = (float*)(ws + 3952896);
    __hip_bfloat16* h     = (__hip_bfloat16*)(ws + 4477184);
    __hip_bfloat16* x1    = (__hip_bfloat16*)(ws + 6574336);
    __hip_bfloat16* xloc  = (__hip_bfloat16*)(ws + 8671488);
    __hip_bfloat16* big   = (__hip_bfloat16*)(ws + 10768640);  // 8 MB: qkv -> f1 -> hid
    __hip_bfloat16* ctxp  = (__hip_bfloat16*)(ws + 19157248);
    __hip_bfloat16* attno = (__hip_bfloat16*)(ws + 21254400);
    __hip_bfloat16* y1    = (__hip_bfloat16*)(ws + 23351552);
    __hip_bfloat16* xfin  = (__hip_bfloat16*)(ws + 25448704);
    float*  Opart  = (float*) (ws + 27545856);   // 16 MB
    float2* MLpart = (float2*)(ws + 44323072);   // 512 KB

    const __hip_bfloat16* xc    = canon + 0;
    const __hip_bfloat16* eac   = canon + 524288;
    const __hip_bfloat16* Wg1   = canon + 655360;   // transposed: [256,128]
    const __hip_bfloat16* bg1   = canon + 688128;
    const __hip_bfloat16* Wg2   = canon + 688384;   // transposed: [256,256]
    const __hip_bfloat16* bg2   = canon + 753920;
    const __hip_bfloat16* ipw   = canon + 754176;   // natural [768,256]
    const __hip_bfloat16* ipb   = canon + 950784;
    const __hip_bfloat16* opw   = canon + 951552;   // natural [256,256]
    const __hip_bfloat16* opb   = canon + 1017088;
    const __hip_bfloat16* ln1g  = canon + 1017344;
    const __hip_bfloat16* ln1b  = canon + 1017600;
    const __hip_bfloat16* fw1   = canon + 1017856;  // transposed: [1024,256]
    const __hip_bfloat16* fb1   = canon + 1280000;
    const __hip_bfloat16* fw2   = canon + 1281024;  // transposed: [256,1024]
    const __hip_bfloat16* fb2   = canon + 1543168;
    const __hip_bfloat16* ln2g  = canon + 1543424;
    const __hip_bfloat16* ln2b  = canon + 1543680;
    const __hip_bfloat16* Wcls  = canon + 1543936;  // natural [256,16]
    const __hip_bfloat16* bcls  = canon + 1548032;
    const __hip_bfloat16* Wd1   = canon + 1548048;  // transposed: [512,256]
    const __hip_bfloat16* bd1   = canon + 1679120;
    const __hip_bfloat16* Wd2   = canon + 1679632;  // natural [512,3]
    const __hip_bfloat16* bd2   = canon + 1681168;

    const void* ei = d_in[1];

    Ptrs24 pt;
    {
        const int map[24] = {0,2,3,4,5,6,7,8,9,10,11,12,13,14,15,16,17,18,19,20,21,22,23,24};
        for (int i = 0; i < 24; i++) pt.p[i] = d_in[map[i]];
    }

    const dim3 b256(256);

    probe_k<<<1, 64, 0, stream>>>((const unsigned*)d_in[11], (const unsigned*)d_in[1], flags);
    cast_all<<<(CAST_TOTAL + 255) / 256, b256, 0, stream>>>(pt, flags, canon);

    deg_init_k<<<16, b256, 0, stream>>>(deg, cnt);
    deg_scat_k<<<512, b256, 0, stream>>>(ei, eac, flags, deg, cnt);
    scan_k<<<1, b256, 0, stream>>>(deg, dinv, cnt, rowptr);
    fill_k<<<512, b256, 0, stream>>>(ei, eac, flags, dinv, rowptr, cnt, csrc, cw);

    // GCN1
    gemm64<false, false><<<dim3(4, 64), b256, 0, stream>>>(xc, Wg1, nullptr, h, 128, 256);
    gcn_agg<true><<<1024, b256, 0, stream>>>(h, dinv, rowptr, csrc, cw, bg1, x1);
    // GCN2
    gemm64<false, false><<<dim3(4, 64), b256, 0, stream>>>(x1, Wg2, nullptr, h, 256, 256);
    gcn_agg<false><<<1024, b256, 0, stream>>>(h, dinv, rowptr, csrc, cw, bg2, xloc);

    // transformer
    gemm64<true, false><<<dim3(12, 64), b256, 0, stream>>>(xloc, ipw, ipb, big, 256, 768);   // qkv
    attn_part<<<dim3(64, 4, KSPLIT), b256, 0, stream>>>(big, Opart, MLpart);
    attn_comb<<<dim3(64, 4), b256, 0, stream>>>(Opart, MLpart, ctxp);
    gemm64<true, false><<<dim3(4, 64), b256, 0, stream>>>(ctxp, opw, opb, attno, 256, 256);
    ln256<false><<<4096, b256, 0, stream>>>(xloc, attno, ln1g, ln1b, nullptr, y1);
    gemm64<true, true><<<dim3(16, 64), b256, 0, stream>>>(y1, fw1, fb1, big, 256, 1024);     // f1
    gemm64<true, false><<<dim3(4, 64), b256, 0, stream>>>(big, fw2, fb2, ctxp, 1024, 256);   // f2
    ln256<true><<<4096, b256, 0, stream>>>(y1, ctxp, ln2g, ln2b, xloc, xfin);

    // heads
    cls16<<<256, b256, 0, stream>>>(xfin, Wcls, bcls, flags, d_out);
    gemm64<true, true><<<dim3(8, 64), b256, 0, stream>>>(xfin, Wd1, bd1, big, 256, 512);     // hid
    reco3<<<64, b256, 0, stream>>>(big, Wd2, bd2, flags, d_out);
}